// Round 1
// baseline (383.228 us; speedup 1.0000x reference)
//
#include <hip/hip_runtime.h>

#define Bn 512
#define Tn 512
#define Cn 64

// Inputs (setup_inputs order):
// 0: emissions (B,T,C) f32   1: tags (B,T) i32   2: mask (B,T) i32
// 3: transitions (C,C) f32   4: start_transitions (C) f32   5: end_transitions (C) f32
// Output: scalar f32 = mean_b(log_denominator - log_numerator)

// ---------------------------------------------------------------------------
// Forward (log-partition) kernel: one wave (64 lanes) per batch element.
// Lane j owns class j. Linear-space recurrence with per-step max renorm:
//   alpha_{t}[j] = (sum_i alpha_{t-1}[i] * expT[i][j]) * exp(emit[t][j])
//   rescale by wave-max, accumulate log(max) into log_scale.
// expT column j kept in 64 VGPRs per lane; alpha broadcast via LDS float4.
// ---------------------------------------------------------------------------
__global__ __launch_bounds__(64) void crf_forward_kernel(
    const float* __restrict__ emissions,
    const int*   __restrict__ mask,
    const float* __restrict__ transitions,
    const float* __restrict__ start_t,
    const float* __restrict__ end_t,
    float*       __restrict__ log_denom)
{
    const int b = blockIdx.x;
    const int j = threadIdx.x;  // 0..63 = class index

    __shared__ float alpha_sh[2][Cn];

    // Precompute exp of transitions column j into registers (once per block).
    float expTcol[Cn];
#pragma unroll
    for (int i = 0; i < Cn; ++i) {
        expTcol[i] = __expf(transitions[i * Cn + j]);
    }

    const float* em = emissions + (size_t)b * Tn * Cn + j;
    const int*   mk = mask + b * Tn;

    // t = 0: lp0 = start[j] + emit[0][j]; go to linear space normalized by max.
    float lp0 = start_t[j] + em[0];
    float m0 = lp0;
#pragma unroll
    for (int off = 32; off > 0; off >>= 1)
        m0 = fmaxf(m0, __shfl_xor(m0, off, 64));
    float log_scale = m0;          // wave-uniform
    alpha_sh[0][j] = __expf(lp0 - m0);
    __syncthreads();

    // Prefetch next emission + mask.
    float e_next = em[Cn];
    int   k_next = mk[1];

    for (int t = 1; t < Tn; ++t) {
        const float e   = __expf(e_next);
        const int   msk = k_next;
        if (t + 1 < Tn) {
            e_next = em[(t + 1) * Cn];
            k_next = mk[t + 1];
        }

        const float* ash = alpha_sh[(t - 1) & 1];
        const float4* a4 = (const float4*)ash;

        // 64-term dot: s[j] = sum_i alpha[i] * expT[i][j], 4 accumulators.
        float acc0 = 0.f, acc1 = 0.f, acc2 = 0.f, acc3 = 0.f;
#pragma unroll
        for (int i = 0; i < Cn / 4; ++i) {
            float4 x = a4[i];
            acc0 = fmaf(x.x, expTcol[4 * i + 0], acc0);
            acc1 = fmaf(x.y, expTcol[4 * i + 1], acc1);
            acc2 = fmaf(x.z, expTcol[4 * i + 2], acc2);
            acc3 = fmaf(x.w, expTcol[4 * i + 3], acc3);
        }
        float s = ((acc0 + acc1) + (acc2 + acc3)) * e;

        // mask==0 -> carry previous alpha unchanged (mask is all-ones here,
        // branch compiles to exec-masked load that never fires).
        if (!msk) s = ash[j];

        // Wave-max renorm (uniform scale is mathematically exact).
        float mx = s;
#pragma unroll
        for (int off = 32; off > 0; off >>= 1)
            mx = fmaxf(mx, __shfl_xor(mx, off, 64));
        const float r = __builtin_amdgcn_rcpf(mx);
        alpha_sh[t & 1][j] = s * r;
        log_scale += __logf(mx);
        __syncthreads();
    }

    // log_denominator = log_scale + log(sum_j alpha[j] * exp(end[j]))
    float v = alpha_sh[(Tn - 1) & 1][j] * __expf(end_t[j]);
#pragma unroll
    for (int off = 32; off > 0; off >>= 1)
        v += __shfl_xor(v, off, 64);
    if (j == 0) log_denom[b] = log_scale + __logf(v);
}

// ---------------------------------------------------------------------------
// Numerator (joint score) kernel: one wave per batch, lanes stride over T.
// ---------------------------------------------------------------------------
__global__ __launch_bounds__(64) void crf_numerator_kernel(
    const float* __restrict__ emissions,
    const int*   __restrict__ tags,
    const int*   __restrict__ mask,
    const float* __restrict__ transitions,
    const float* __restrict__ start_t,
    const float* __restrict__ end_t,
    float*       __restrict__ num_out)
{
    const int b = blockIdx.x;
    const int l = threadIdx.x;
    const int*   tg = tags + b * Tn;
    const int*   mk = mask + b * Tn;
    const float* em = emissions + (size_t)b * Tn * Cn;

    float sum  = 0.f;
    int   mcnt = 0;
    for (int t = l; t < Tn; t += 64) {
        const int tag_t = tg[t];
        mcnt += mk[t];
        if (t >= 1 && mk[t]) {
            const int tag_p = tg[t - 1];
            sum += transitions[tag_p * Cn + tag_t] + em[t * Cn + tag_t];
        }
    }
#pragma unroll
    for (int off = 32; off > 0; off >>= 1) {
        sum  += __shfl_xor(sum, off, 64);
        mcnt += __shfl_xor(mcnt, off, 64);
    }
    if (l == 0) {
        const int last_idx = mcnt - 1;            // sum(mask) - 1
        const int t0 = tg[0];
        const int tl = tg[last_idx];
        const float score0 = start_t[t0] + em[t0];
        num_out[b] = score0 + sum + end_t[tl];
    }
}

// ---------------------------------------------------------------------------
// Final reduction: mean over B of (log_denom - num).
// ---------------------------------------------------------------------------
__global__ __launch_bounds__(512) void crf_final_kernel(
    const float* __restrict__ ld,
    const float* __restrict__ num,
    float* __restrict__ out)
{
    __shared__ float sh[8];
    const int i = threadIdx.x;  // 0..511
    float v = ld[i] - num[i];
#pragma unroll
    for (int off = 32; off > 0; off >>= 1)
        v += __shfl_xor(v, off, 64);
    if ((i & 63) == 0) sh[i >> 6] = v;
    __syncthreads();
    if (i == 0) {
        float s = 0.f;
#pragma unroll
        for (int k = 0; k < 8; ++k) s += sh[k];
        out[0] = s * (1.0f / Bn);
    }
}

extern "C" void kernel_launch(void* const* d_in, const int* in_sizes, int n_in,
                              void* d_out, int out_size, void* d_ws, size_t ws_size,
                              hipStream_t stream)
{
    const float* emissions   = (const float*)d_in[0];
    const int*   tags        = (const int*)d_in[1];
    const int*   mask        = (const int*)d_in[2];
    const float* transitions = (const float*)d_in[3];
    const float* start_t     = (const float*)d_in[4];
    const float* end_t       = (const float*)d_in[5];

    float* ld  = (float*)d_ws;        // 512 floats
    float* num = ld + Bn;             // 512 floats

    crf_forward_kernel<<<Bn, Cn, 0, stream>>>(emissions, mask, transitions,
                                              start_t, end_t, ld);
    crf_numerator_kernel<<<Bn, 64, 0, stream>>>(emissions, tags, mask, transitions,
                                                start_t, end_t, num);
    crf_final_kernel<<<1, 512, 0, stream>>>(ld, num, (float*)d_out);
}

// Round 2
// 277.590 us; speedup vs baseline: 1.3806x; 1.3806x over previous
//
#include <hip/hip_runtime.h>

#define Bn 512
#define Tn 512
#define Cn 64

// Inputs (setup_inputs order):
// 0: emissions (B,T,C) f32   1: tags (B,T) i32   2: mask (B,T) i32
// 3: transitions (C,C) f32   4: start_transitions (C) f32   5: end_transitions (C) f32
// Output: scalar f32 = mean_b(log_denominator - log_numerator)

// DPP-based wave64 max reduce. Stages: xor1 (quad_perm [1,0,3,2]), xor2
// (quad_perm [2,3,0,1]), xor4 (row_half_mirror), xor8 (row_mirror) -> each
// 16-lane row fully reduced; row_bcast15 merges row pairs, row_bcast31 merges
// halves -> lanes 48..63 hold the full max; readlane(63) broadcasts.
template <int CTRL>
__device__ __forceinline__ float fmax_dpp(float v) {
    int mi = __builtin_amdgcn_update_dpp(__float_as_int(v), __float_as_int(v),
                                         CTRL, 0xF, 0xF, false);
    return fmaxf(v, __int_as_float(mi));
}

__device__ __forceinline__ float wave_max64(float v) {
    v = fmax_dpp<0x0B1>(v);  // quad_perm [1,0,3,2]  (xor 1)
    v = fmax_dpp<0x04E>(v);  // quad_perm [2,3,0,1]  (xor 2)
    v = fmax_dpp<0x141>(v);  // row_half_mirror      (xor 4)
    v = fmax_dpp<0x140>(v);  // row_mirror           (xor 8)
    v = fmax_dpp<0x142>(v);  // row_bcast15          (rows 0->1, 2->3)
    v = fmax_dpp<0x143>(v);  // row_bcast31          (half 0 -> half 1)
    return __int_as_float(__builtin_amdgcn_readlane(__float_as_int(v), 63));
}

// One wave per batch element. Lane j owns class j. Linear-space recurrence:
//   s_t[j] = (sum_i alpha_{t-1}[i] * expT[i][j]) * exp(emit[t][j])
// Renormalize by wave-max only every 4 steps (growth bound ~1e23 << fp32 max;
// uniform scaling is exact, log(max) accumulates into log_scale).
// Single-wave block: no s_barrier; per-wave DS ops are in-order, one explicit
// lgkmcnt(0) wait after the alpha write as insurance.
__global__ __launch_bounds__(64) void crf_fused_kernel(
    const float* __restrict__ emissions,
    const int*   __restrict__ tags,
    const int*   __restrict__ mask,
    const float* __restrict__ transitions,
    const float* __restrict__ start_t,
    const float* __restrict__ end_t,
    float*       __restrict__ out)
{
    const int b = blockIdx.x;
    const int j = threadIdx.x;  // class index

    __shared__ float alpha_sh[Cn];

    const float* em  = emissions + (size_t)b * Tn * Cn + j;
    const float* em0 = emissions + (size_t)b * Tn * Cn;
    const int*   mk  = mask + b * Tn;
    const int*   tg  = tags + b * Tn;

    // ---------------- numerator (joint score), lanes stride over T ---------
    float nsum = 0.f;
    int   mcnt = 0;
    for (int t = j; t < Tn; t += 64) {
        const int tag_t = tg[t];
        const int m_t   = mk[t];
        mcnt += m_t;
        if (t >= 1 && m_t) {
            const int tag_p = tg[t - 1];
            nsum += transitions[tag_p * Cn + tag_t] + em0[t * Cn + tag_t];
        }
    }
#pragma unroll
    for (int off = 32; off > 0; off >>= 1) {
        nsum += __shfl_xor(nsum, off, 64);
        mcnt += __shfl_xor(mcnt, off, 64);
    }

    // ---------------- expT column j in registers ---------------------------
    float expTcol[Cn];
#pragma unroll
    for (int i = 0; i < Cn; ++i) expTcol[i] = __expf(transitions[i * Cn + j]);

    // ---------------- t = 0 ------------------------------------------------
    float lp0 = start_t[j] + em[0];
    const float m0 = wave_max64(lp0);
    float log_scale = m0;                 // wave-uniform
    float a_self = __expf(lp0 - m0);
    alpha_sh[j] = a_self;
    __asm__ volatile("s_waitcnt lgkmcnt(0)" ::: "memory");

    // Prefetch group 0 (t = 1..4) emissions + mask.
    float cur_e[4];
    int   cur_m[4];
#pragma unroll
    for (int k = 0; k < 4; ++k) {
        cur_e[k] = em[(size_t)(1 + k) * Cn];
        cur_m[k] = mk[1 + k];
    }

    for (int g = 0; g < 128; ++g) {
        // Prefetch next group (4 steps ahead -> HBM latency covered).
        float nxt_e[4];
        int   nxt_m[4];
#pragma unroll
        for (int k = 0; k < 4; ++k) {
            const int t = 4 * g + 5 + k;
            nxt_e[k] = (t < Tn) ? em[(size_t)t * Cn] : 0.f;
            nxt_m[k] = (t < Tn) ? mk[t] : 0;
        }
        // exp() of this group's emissions, off the critical path.
        float ex[4];
#pragma unroll
        for (int k = 0; k < 4; ++k) ex[k] = __expf(cur_e[k]);

#pragma unroll
        for (int k = 0; k < 4; ++k) {
            const int t = 4 * g + 1 + k;
            if (t < Tn) {
                const float4* a4 = (const float4*)alpha_sh;
                float acc0 = 0.f, acc1 = 0.f, acc2 = 0.f, acc3 = 0.f;
#pragma unroll
                for (int i = 0; i < Cn / 4; ++i) {
                    const float4 x = a4[i];
                    acc0 = fmaf(x.x, expTcol[4 * i + 0], acc0);
                    acc1 = fmaf(x.y, expTcol[4 * i + 1], acc1);
                    acc2 = fmaf(x.z, expTcol[4 * i + 2], acc2);
                    acc3 = fmaf(x.w, expTcol[4 * i + 3], acc3);
                }
                float s = ((acc0 + acc1) + (acc2 + acc3)) * ex[k];
                if (!cur_m[k]) s = a_self;  // mask==0: carry previous alpha
                if (k == 3) {               // renorm every 4th step
                    const float mx = wave_max64(s);
                    s *= __builtin_amdgcn_rcpf(mx);
                    log_scale += __logf(mx);
                }
                a_self = s;
                alpha_sh[j] = s;
                __asm__ volatile("s_waitcnt lgkmcnt(0)" ::: "memory");
            }
        }
#pragma unroll
        for (int k = 0; k < 4; ++k) {
            cur_e[k] = nxt_e[k];
            cur_m[k] = nxt_m[k];
        }
    }

    // ---------------- finalize --------------------------------------------
    // Last renorm at t=508; 3 raw steps -> v <= ~1e21, safe in fp32.
    float v = a_self * __expf(end_t[j]);
#pragma unroll
    for (int off = 32; off > 0; off >>= 1) v += __shfl_xor(v, off, 64);
    const float denom = log_scale + __logf(v);

    if (j == 0) {
        const int last_idx = mcnt - 1;  // sum(mask) - 1
        const int t0 = tg[0];
        const int tl = tg[last_idx];
        const float num = start_t[t0] + em0[t0] + nsum + end_t[tl];
        atomicAdd(out, (denom - num) * (1.0f / Bn));
    }
}

__global__ void crf_zero_kernel(float* out) { out[0] = 0.f; }

extern "C" void kernel_launch(void* const* d_in, const int* in_sizes, int n_in,
                              void* d_out, int out_size, void* d_ws, size_t ws_size,
                              hipStream_t stream)
{
    const float* emissions   = (const float*)d_in[0];
    const int*   tags        = (const int*)d_in[1];
    const int*   mask        = (const int*)d_in[2];
    const float* transitions = (const float*)d_in[3];
    const float* start_t     = (const float*)d_in[4];
    const float* end_t       = (const float*)d_in[5];

    crf_zero_kernel<<<1, 1, 0, stream>>>((float*)d_out);
    crf_fused_kernel<<<Bn, Cn, 0, stream>>>(emissions, tags, mask, transitions,
                                            start_t, end_t, (float*)d_out);
}